// Round 16
// baseline (134.849 us; speedup 1.0000x reference)
//
#include <hip/hip_runtime.h>
#include <math.h>

#define N_ROWS 1024
#define RANK   8
#define M_COLS 4096
#define NBLOCKS 1024
#define R_ROWS 2
#define T_PTS  2
#define M_STRIDE 1024

// Static device scratch (fully overwritten every call before read).
__device__ float2 g_Hft[RANK * M_COLS];    // FFT of softplus(H), 256 KB
__device__ float4 g_Tab4[N_ROWS * RANK];   // {vr, vi, wcr, wci}, 128 KB
__device__ float2 g_Tab2[N_ROWS * RANK];   // {ws, tau}, 64 KB
__device__ int    g_barA = 0;              // barrier arrive counter
__device__ int    g_barB = 0;              // barrier depart counter (self-reset)

// fast softplus: 2 trans + ~4 VALU. exact for x>20; inputs are ~N(0,1).
__device__ __forceinline__ float softplus_f(float x) {
    float t = __expf(x);
    float r = 0.69314718056f * __log2f(1.0f + t);
    return (x > 20.0f) ? x : r;
}
// hw trig: v_sin/v_cos compute sin/cos(2*pi*x), x in revolutions.
__device__ __forceinline__ float sin_rev(float x) { return __builtin_amdgcn_sinf(x); }
__device__ __forceinline__ float cos_rev(float x) { return __builtin_amdgcn_cosf(x); }
__device__ __forceinline__ float fract_f(float x) { return __builtin_amdgcn_fractf(x); }
// block-uniform float -> SGPR
__device__ __forceinline__ float rfl(float x) {
    return __int_as_float(__builtin_amdgcn_readfirstlane(__float_as_int(x)));
}

// Device-scope grid barrier, self-resetting across graph replays.
// Safe: all NBLOCKS blocks are co-resident (LDS 32KB -> 5 blocks/CU -> 1280
// slots; launch_bounds caps VGPR at 128 -> >=4 blocks/CU -> >=1024 slots).
__device__ __forceinline__ void grid_barrier() {
    __syncthreads();
    if (threadIdx.x == 0) {
        __threadfence();    // release g_Hft/g_Tab* device-wide
        __hip_atomic_fetch_add(&g_barA, 1, __ATOMIC_ACQ_REL, __HIP_MEMORY_SCOPE_AGENT);
        while (__hip_atomic_load(&g_barA, __ATOMIC_ACQUIRE, __HIP_MEMORY_SCOPE_AGENT) < NBLOCKS)
            __builtin_amdgcn_s_sleep(8);
        __threadfence();    // acquire before reading other blocks' writes
        int bb = __hip_atomic_fetch_add(&g_barB, 1, __ATOMIC_ACQ_REL, __HIP_MEMORY_SCOPE_AGENT);
        if (bb == NBLOCKS - 1) {            // last one out resets for next replay
            __hip_atomic_store(&g_barA, 0, __ATOMIC_RELAXED, __HIP_MEMORY_SCOPE_AGENT);
            __hip_atomic_store(&g_barB, 0, __ATOMIC_RELAXED, __HIP_MEMORY_SCOPE_AGENT);
        }
    }
    __syncthreads();
}

// ---------------------------------------------------------------------------
// One fused kernel.
// Phase 1: blocks 0..127 = softplus(H) + 64x64 DFT -> g_Hft (R13-proven);
//          blocks 128..159 = Tab4/Tab2; blocks 160..1023 idle.
// Barrier.
// Phase 2: block b: bx=b&3 -> m0 = bx*256+tid; stage 32KB Hft slice to LDS;
//          r2 in {0,1}: rows n0 = ((b>>2)+r2*256)*2 — R13 math, h from LDS.
// ---------------------------------------------------------------------------
__global__ __launch_bounds__(256, 4)
void shiftnmf_fused(const float* __restrict__ H, const float* __restrict__ W,
                    const float* __restrict__ tau, float* __restrict__ out) {
    __shared__ __align__(16) unsigned char smem[32768];   // union: fft 18KB / sHft 32KB
    const int tid = threadIdx.x;
    const int b   = blockIdx.x;

    // ---------------- phase 1 ----------------
    if (b < 128) {
        float*  sHs = (float*)smem;                       // 16 KB
        float2* sY  = (float2*)(smem + 16384);            // 2 KB
        int d   = b >> 4;
        int m0b = (b & 15) << 2;

        const float4* Hrow4 = (const float4*)(H + d * M_COLS);
        #pragma unroll
        for (int p = 0; p < 4; ++p) {
            int i = p * 256 + tid;
            float4 h4 = Hrow4[i];
            sHs[i*4+0] = softplus_f(h4.x);
            sHs[i*4+1] = softplus_f(h4.y);
            sHs[i*4+2] = softplus_f(h4.z);
            sHs[i*4+3] = softplus_f(h4.w);
        }
        __syncthreads();
        {   // stage A
            int k0 = tid & 63, j = tid >> 6;
            int m0 = m0b + j;
            float mrev = (float)m0 * (1.0f / 64.0f);
            float rr =  cos_rev(mrev);
            float ri = -sin_rev(mrev);
            float twr = 1.0f, twi = 0.0f;
            float ar = 0.0f, ai = 0.0f;
            #pragma unroll
            for (int k1 = 0; k1 < 64; ++k1) {
                float v = sHs[(k1 << 6) + k0];
                ar = fmaf(v, twr, ar);
                ai = fmaf(v, twi, ai);
                float nr = fmaf(twr, rr, -(twi * ri));
                twi      = fmaf(twr, ri,   twi * rr);
                twr = nr;
            }
            sY[(j << 6) + k0] = make_float2(ar, ai);
        }
        __syncthreads();
        {   // stage B
            int m1 = tid & 63, j = tid >> 6;
            int m  = (m1 << 6) + m0b + j;
            float mrev = (float)m * (1.0f / 4096.0f);
            float rr =  cos_rev(mrev);
            float ri = -sin_rev(mrev);
            float twr = 1.0f, twi = 0.0f;
            float ar = 0.0f, ai = 0.0f;
            #pragma unroll
            for (int k0 = 0; k0 < 64; ++k0) {
                float2 y = sY[(j << 6) + k0];
                ar = fmaf(y.x, twr, fmaf(-y.y, twi, ar));
                ai = fmaf(y.x, twi, fmaf( y.y, twr, ai));
                float nr = fmaf(twr, rr, -(twi * ri));
                twi      = fmaf(twr, ri,   twi * rr);
                twr = nr;
            }
            g_Hft[d * M_COLS + m] = make_float2(ar, ai);
        }
    } else if (b < 160) {                 // Tab4/Tab2: 32 blocks x 256 = 8192
        int t = (b - 128) * 256 + tid;
        float w  = softplus_f(W[t]);
        float tv = tau[t];
        float rv = fract_f(tv * ((float)M_STRIDE / (float)M_COLS));  // tv/4
        float4 t4;
        t4.x = cos_rev(rv);               // step = e^{+i 2pi tau*1024/M}
        t4.y = sin_rev(rv);
        float rc = fract_f(-tv);          // e^{-2pi i tau}
        t4.z = w * cos_rev(rc);           // wcr
        t4.w = w * sin_rev(rc);           // wci
        g_Tab4[t] = t4;
        g_Tab2[t] = make_float2(w, tv);
    }

    grid_barrier();

    // ---------------- phase 2 ----------------
    float2* sHft = (float2*)smem;         // [8][2][256] = 32 KB
    const int bx = b & 3;
    const int m0 = bx * 256 + tid;        // 0..1023 ; m_j = 1 + m0 + j*1024
    const float fm0 = (float)(1 + m0) * (1.0f / (float)M_COLS);

    #pragma unroll
    for (int u = 0; u < 16; ++u) {        // stage Hft slice, coalesced 8B/lane
        int idx = u * 256 + tid;
        int dd = idx >> 9;
        int jj = (idx >> 8) & 1;
        sHft[idx] = g_Hft[dd * M_COLS + 1 + jj * M_STRIDE + bx * 256 + tid];
    }
    __syncthreads();

    #pragma unroll 1
    for (int r2 = 0; r2 < 2; ++r2) {
        int n0 = ((b >> 2) + r2 * 256) * 2;

        float accm[R_ROWS][T_PTS], accx[R_ROWS][T_PTS];
        #pragma unroll
        for (int r = 0; r < R_ROWS; ++r)
            #pragma unroll
            for (int j = 0; j < T_PTS; ++j) { accm[r][j] = 0.0f; accx[r][j] = 0.0f; }

        #pragma unroll
        for (int d = 0; d < RANK; ++d) {
            float ur[R_ROWS], ui[R_ROWS];
            float vr[R_ROWS], vi[R_ROWS];
            float ws[R_ROWS], wcr[R_ROWS], wci[R_ROWS];
            #pragma unroll
            for (int r = 0; r < R_ROWS; ++r) {
                int nd = (n0 + r) * RANK + d;
                float4 t4 = g_Tab4[nd];               // block-uniform
                vr[r]  = rfl(t4.x);  vi[r]  = rfl(t4.y);
                wcr[r] = rfl(t4.z);  wci[r] = rfl(t4.w);
                ws[r]  = rfl(g_Tab2[nd].x);
                float tv = rfl(g_Tab2[nd].y);
                float r0 = fract_f(tv * fm0);         // only per-thread trig
                ur[r] = cos_rev(r0);
                ui[r] = sin_rev(r0);
            }
            #pragma unroll
            for (int j = 0; j < T_PTS; ++j) {
                float2 h = sHft[(d << 9) + (j << 8) + tid];   // LDS, conflict-free
                #pragma unroll
                for (int r = 0; r < R_ROWS; ++r) {
                    float t1v = ui[r] * h.y;
                    float zr = fmaf(ur[r], h.x, t1v);         // Re(conj(u)h)
                    float t2v = ui[r] * h.x;
                    float zi = fmaf(ur[r], h.y, -t2v);        // Im(conj(u)h)
                    accm[r][j] = fmaf(ws[r],  zr, accm[r][j]);
                    accx[r][j] = fmaf(wcr[r], zr, fmaf(wci[r], zi, accx[r][j]));
                    if (j < T_PTS - 1) {                      // u *= v
                        float nr = fmaf(ur[r], vr[r], -(ui[r] * vi[r]));
                        ui[r]    = fmaf(ur[r], vi[r],   ui[r] * vr[r]);
                        ur[r]    = nr;
                    }
                }
            }
        }

        #pragma unroll
        for (int r = 0; r < R_ROWS; ++r) {
            float* op = out + (n0 + r) * M_COLS;
            #pragma unroll
            for (int j = 0; j < T_PTS; ++j)
                op[1 + m0 + j * M_STRIDE] = accm[r][j];       // m in [1,2048]
            #pragma unroll
            for (int j = 0; j < T_PTS; ++j)
                op[4095 - m0 - j * M_STRIDE] = accx[r][j];    // [2048,4095]
        }

        if (bx == 0 && tid == 0) {        // column 0, direct
            #pragma unroll
            for (int r = 0; r < R_ROWS; ++r) {
                int n = n0 + r;
                float a = 0.0f;
                #pragma unroll
                for (int d = 0; d < RANK; ++d)
                    a = fmaf(g_Tab2[n * RANK + d].x, g_Hft[d * M_COLS].x, a);
                out[n * M_COLS] = a;
            }
        }
    }
}

extern "C" void kernel_launch(void* const* d_in, const int* in_sizes, int n_in,
                              void* d_out, int out_size, void* d_ws, size_t ws_size,
                              hipStream_t stream) {
    const float* W   = (const float*)d_in[0];   // [1024, 8]
    const float* H   = (const float*)d_in[1];   // [8, 4096]
    const float* tau = (const float*)d_in[2];   // [1024, 8]

    shiftnmf_fused<<<dim3(NBLOCKS), dim3(256), 0, stream>>>(H, W, tau, (float*)d_out);
}

// Round 17
// 19.408 us; speedup vs baseline: 6.9481x; 6.9481x over previous
//
#include <hip/hip_runtime.h>
#include <math.h>

#define N_ROWS 1024
#define RANK   8
#define M_COLS 4096

#define R_ROWS   2      // n-rows per thread
#define T_PTS    2      // direct points per thread in [1,2048], stride 1024
#define M_STRIDE 1024

// Static device scratch (fully overwritten every call before read).
__device__ float2 g_Hft[RANK * M_COLS];    // full FFT of softplus(H), 256 KB
__device__ float4 g_Tab4[N_ROWS * RANK];   // {vr, vi, wcr, wci} per (n,d), 128 KB
__device__ float2 g_Tab2[N_ROWS * RANK];   // {ws, tau}          per (n,d),  64 KB

// fast softplus: 2 trans + ~4 VALU. exact for x>20; inputs are ~N(0,1).
__device__ __forceinline__ float softplus_f(float x) {
    float t = __expf(x);
    float r = 0.69314718056f * __log2f(1.0f + t);
    return (x > 20.0f) ? x : r;
}
// hw trig: v_sin/v_cos compute sin/cos(2*pi*x), x in revolutions.
__device__ __forceinline__ float sin_rev(float x) { return __builtin_amdgcn_sinf(x); }
__device__ __forceinline__ float cos_rev(float x) { return __builtin_amdgcn_cosf(x); }
__device__ __forceinline__ float fract_f(float x) { return __builtin_amdgcn_fractf(x); }
// block-uniform float -> SGPR
__device__ __forceinline__ float rfl(float x) {
    return __int_as_float(__builtin_amdgcn_readfirstlane(__float_as_int(x)));
}

// ---------------------------------------------------------------------------
// Fused FFT: softplus(H) + 64x64 Cooley-Tukey DFT -> g_Hft. Side-job (blocks
// 0..31): per-(n,d) trig table. (R13-proven, unchanged)
// ---------------------------------------------------------------------------
__global__ void fft_fused(const float* __restrict__ H,
                          const float* __restrict__ W,
                          const float* __restrict__ tau) {
    __shared__ float  sHs[M_COLS];        // 16 KB
    __shared__ float2 sY[4 * 64];         // [j][k0], 2 KB

    int tid = threadIdx.x;
    int d   = blockIdx.x >> 4;
    int m0b = (blockIdx.x & 15) << 2;

    if (blockIdx.x < 32) {                // table side-job (no dependency)
        int t = blockIdx.x * 256 + tid;   // (n,d) pair index < 8192
        float w  = softplus_f(W[t]);
        float tv = tau[t];
        float rv = fract_f(tv * ((float)M_STRIDE / (float)M_COLS));  // tv/4
        float4 t4;
        t4.x = cos_rev(rv);               // step = e^{+i 2pi tau*1024/M}
        t4.y = sin_rev(rv);
        float rc = fract_f(-tv);          // e^{-2pi i tau}
        t4.z = w * cos_rev(rc);           // wcr
        t4.w = w * sin_rev(rc);           // wci
        g_Tab4[t] = t4;
        g_Tab2[t] = make_float2(w, tv);
    }

    const float4* Hrow4 = (const float4*)(H + d * M_COLS);
    #pragma unroll
    for (int p = 0; p < 4; ++p) {
        int i = p * 256 + tid;            // 1024 float4 per row
        float4 h4 = Hrow4[i];
        sHs[i*4+0] = softplus_f(h4.x);
        sHs[i*4+1] = softplus_f(h4.y);
        sHs[i*4+2] = softplus_f(h4.z);
        sHs[i*4+3] = softplus_f(h4.w);
    }
    __syncthreads();

    {   // stage A
        int k0 = tid & 63, j = tid >> 6;
        int m0 = m0b + j;
        float mrev = (float)m0 * (1.0f / 64.0f);
        float rr =  cos_rev(mrev);
        float ri = -sin_rev(mrev);        // step = e^{-2pi i m0/64}
        float twr = 1.0f, twi = 0.0f;
        float ar = 0.0f, ai = 0.0f;
        #pragma unroll
        for (int k1 = 0; k1 < 64; ++k1) {
            float v = sHs[(k1 << 6) + k0];
            ar = fmaf(v, twr, ar);
            ai = fmaf(v, twi, ai);
            float nr = fmaf(twr, rr, -(twi * ri));
            twi      = fmaf(twr, ri,   twi * rr);
            twr = nr;
        }
        sY[(j << 6) + k0] = make_float2(ar, ai);
    }
    __syncthreads();

    {   // stage B
        int m1 = tid & 63, j = tid >> 6;
        int m  = (m1 << 6) + m0b + j;
        float mrev = (float)m * (1.0f / 4096.0f);
        float rr =  cos_rev(mrev);
        float ri = -sin_rev(mrev);        // step = e^{-2pi i m/4096}
        float twr = 1.0f, twi = 0.0f;
        float ar = 0.0f, ai = 0.0f;
        #pragma unroll
        for (int k0 = 0; k0 < 64; ++k0) {
            float2 y = sY[(j << 6) + k0];
            ar = fmaf(y.x, twr, fmaf(-y.y, twi, ar));
            ai = fmaf(y.x, twi, fmaf( y.y, twr, ai));
            float nr = fmaf(twr, rr, -(twi * ri));
            twi      = fmaf(twr, ri,   twi * rr);
            twr = nr;
        }
        g_Hft[d * M_COLS + m] = make_float2(ar, ai);
    }
}

// ---------------------------------------------------------------------------
// Main (R13 math, single change: ALL 16 h-loads issued up-front into
// registers — one latency exposure instead of 8 serial ones).
// For m = 1+m0+j*1024:  u = e^{+i 2pi tau m/M}
//   zr = ur*hr + ui*hi ; zi = ur*hi - ui*hr
//   Re V[n,m]      += ws * zr
//   Re V[n,4096-m] += wcr*zr + wci*zi      (Hermitian mirror, R12-validated)
// grid (4,512) = 2048 blocks = 8 waves/SIMD; est. ~56 live VGPRs (<64).
// ---------------------------------------------------------------------------
__global__ void shiftnmf_main(float* __restrict__ out) {
    int tid = threadIdx.x;
    int m0  = blockIdx.x * 256 + tid;     // 0..1023 ; m_j = 1 + m0 + j*1024
    int n0  = blockIdx.y * R_ROWS;

    float fm0 = (float)(1 + m0) * (1.0f / (float)M_COLS);

    // prefetch all h: 16 independent loads, issued back-to-back
    float2 h[RANK][T_PTS];
    #pragma unroll
    for (int d = 0; d < RANK; ++d)
        #pragma unroll
        for (int j = 0; j < T_PTS; ++j)
            h[d][j] = g_Hft[d * M_COLS + 1 + m0 + j * M_STRIDE];

    float accm[R_ROWS][T_PTS];            // direct outputs, m
    float accx[R_ROWS][T_PTS];            // mirror outputs, 4096-m
    #pragma unroll
    for (int r = 0; r < R_ROWS; ++r)
        #pragma unroll
        for (int j = 0; j < T_PTS; ++j) { accm[r][j] = 0.0f; accx[r][j] = 0.0f; }

    #pragma unroll
    for (int d = 0; d < RANK; ++d) {
        float ur[R_ROWS], ui[R_ROWS];                 // unit phasor (per-lane)
        float vr[R_ROWS], vi[R_ROWS];                 // step (SGPR)
        float ws[R_ROWS], wcr[R_ROWS], wci[R_ROWS];   // weights (SGPR)
        #pragma unroll
        for (int r = 0; r < R_ROWS; ++r) {
            int nd = (n0 + r) * RANK + d;
            float4 t4 = g_Tab4[nd];                   // block-uniform -> s_load
            vr[r]  = rfl(t4.x);  vi[r]  = rfl(t4.y);
            wcr[r] = rfl(t4.z);  wci[r] = rfl(t4.w);
            ws[r]  = rfl(g_Tab2[nd].x);
            float tv = rfl(g_Tab2[nd].y);
            float r0 = fract_f(tv * fm0);             // only per-thread trig
            ur[r] = cos_rev(r0);                      // u = e^{+i 2pi tau m_0/M}
            ui[r] = sin_rev(r0);
        }

        #pragma unroll
        for (int j = 0; j < T_PTS; ++j) {
            float hx = h[d][j].x, hy = h[d][j].y;
            #pragma unroll
            for (int r = 0; r < R_ROWS; ++r) {
                float t1v = ui[r] * hy;
                float zr = fmaf(ur[r], hx, t1v);      // Re(conj(u)h)
                float t2v = ui[r] * hx;
                float zi = fmaf(ur[r], hy, -t2v);     // Im(conj(u)h)
                accm[r][j] = fmaf(ws[r],  zr, accm[r][j]);
                accx[r][j] = fmaf(wcr[r], zr, fmaf(wci[r], zi, accx[r][j]));
                if (j < T_PTS - 1) {                  // u *= v (skip dead last)
                    float nr = fmaf(ur[r], vr[r], -(ui[r] * vi[r]));
                    ui[r]    = fmaf(ur[r], vi[r],   ui[r] * vr[r]);
                    ur[r]    = nr;
                }
            }
        }
    }

    #pragma unroll
    for (int r = 0; r < R_ROWS; ++r) {
        float* op = out + (n0 + r) * M_COLS;
        #pragma unroll
        for (int j = 0; j < T_PTS; ++j)
            op[1 + m0 + j * M_STRIDE] = accm[r][j];    // m in [1,2048]
        #pragma unroll
        for (int j = 0; j < T_PTS; ++j)
            op[4095 - m0 - j * M_STRIDE] = accx[r][j]; // 4096-m in [2048,4095]
    }

    if (blockIdx.x == 0 && tid == 0) {                // column 0, direct
        #pragma unroll
        for (int r = 0; r < R_ROWS; ++r) {
            int n = n0 + r;
            float a = 0.0f;
            #pragma unroll
            for (int d = 0; d < RANK; ++d)
                a = fmaf(g_Tab2[n * RANK + d].x, g_Hft[d * M_COLS].x, a);
            out[n * M_COLS] = a;
        }
    }
}

extern "C" void kernel_launch(void* const* d_in, const int* in_sizes, int n_in,
                              void* d_out, int out_size, void* d_ws, size_t ws_size,
                              hipStream_t stream) {
    const float* W   = (const float*)d_in[0];   // [1024, 8]
    const float* H   = (const float*)d_in[1];   // [8, 4096]
    const float* tau = (const float*)d_in[2];   // [1024, 8]

    fft_fused<<<dim3(RANK * 16), dim3(256), 0, stream>>>(H, W, tau);

    dim3 grid(M_COLS / 2 / (256 * T_PTS), N_ROWS / R_ROWS);  // (4, 512)
    shiftnmf_main<<<grid, dim3(256), 0, stream>>>((float*)d_out);
}

// Round 18
// 18.839 us; speedup vs baseline: 7.1578x; 1.0302x over previous
//
#include <hip/hip_runtime.h>
#include <math.h>

#define N_ROWS 1024
#define RANK   8
#define M_COLS 4096

#define R_ROWS   2      // n-rows per thread
#define T_PTS    2      // direct points per thread in [1,2048], stride 1024
#define M_STRIDE 1024

// Static device scratch (fully overwritten every call before read).
__device__ float2 g_Hft[RANK * M_COLS];    // full FFT of softplus(H), 256 KB
__device__ float4 g_Tab4[N_ROWS * RANK];   // {vr, vi, wcr, wci} per (n,d), 128 KB
__device__ float2 g_Tab2[N_ROWS * RANK];   // {ws, tau}          per (n,d),  64 KB

// fast softplus: 2 trans + ~4 VALU. exact for x>20; inputs are ~N(0,1).
__device__ __forceinline__ float softplus_f(float x) {
    float t = __expf(x);
    float r = 0.69314718056f * __log2f(1.0f + t);
    return (x > 20.0f) ? x : r;
}
// hw trig: v_sin/v_cos compute sin/cos(2*pi*x), x in revolutions.
__device__ __forceinline__ float sin_rev(float x) { return __builtin_amdgcn_sinf(x); }
__device__ __forceinline__ float cos_rev(float x) { return __builtin_amdgcn_cosf(x); }
__device__ __forceinline__ float fract_f(float x) { return __builtin_amdgcn_fractf(x); }
// block-uniform float -> SGPR
__device__ __forceinline__ float rfl(float x) {
    return __int_as_float(__builtin_amdgcn_readfirstlane(__float_as_int(x)));
}

// ---------------------------------------------------------------------------
// Widened fused FFT: 128 blocks x 512 threads (was x256). Split-sum:
//   stage A: thread (k0, m0j, half) sums 32 k1-terms; LDS combine.
//   stage B: thread (m1, m0j, half) sums 32 k0-terms; LDS combine; write Hft.
// Per-thread issue ~halved; 8 waves/block = 2 waves/SIMD on active CUs.
// Blocks 0..15 also fill g_Tab4/g_Tab2 (8192 entries, 512 thr each).
// ---------------------------------------------------------------------------
__global__ void fft_fused(const float* __restrict__ H,
                          const float* __restrict__ W,
                          const float* __restrict__ tau) {
    __shared__ float  sHs[M_COLS];        // 16 KB
    __shared__ float2 sY [4 * 64];        // stage-A combined, [m0j][k0], 2 KB
    __shared__ float2 sP [512];           // partials (A and B), 4 KB

    const int tid = threadIdx.x;          // 0..511
    const int b   = blockIdx.x;           // 0..127
    const int d   = b >> 4;
    const int m0b = (b & 15) << 2;

    if (b < 16) {                         // table side-job: 16 x 512 = 8192
        int t = b * 512 + tid;
        float w  = softplus_f(W[t]);
        float tv = tau[t];
        float rv = fract_f(tv * ((float)M_STRIDE / (float)M_COLS));  // tv/4
        float4 t4;
        t4.x = cos_rev(rv);               // step = e^{+i 2pi tau*1024/M}
        t4.y = sin_rev(rv);
        float rc = fract_f(-tv);          // e^{-2pi i tau}
        t4.z = w * cos_rev(rc);           // wcr
        t4.w = w * sin_rev(rc);           // wci
        g_Tab4[t] = t4;
        g_Tab2[t] = make_float2(w, tv);
    }

    // load + softplus H row: 1024 float4 over 512 threads -> 2 each
    const float4* Hrow4 = (const float4*)(H + d * M_COLS);
    #pragma unroll
    for (int p = 0; p < 2; ++p) {
        int i = p * 512 + tid;
        float4 h4 = Hrow4[i];
        sHs[i*4+0] = softplus_f(h4.x);
        sHs[i*4+1] = softplus_f(h4.y);
        sHs[i*4+2] = softplus_f(h4.z);
        sHs[i*4+3] = softplus_f(h4.w);
    }
    __syncthreads();

    {   // stage A partial: tid = half*256 + m0j*64 + k0
        int k0   = tid & 63;
        int m0j  = (tid >> 6) & 3;
        int half = tid >> 8;
        int m0   = m0b + m0j;
        float mrev = (float)m0 * (1.0f / 64.0f);
        float rr =  cos_rev(mrev);
        float ri = -sin_rev(mrev);        // rot = e^{-2pi i m0/64}
        // init tw = e^{-2pi i (32*half*m0)/64} = (-1)^{half*m0} (exact)
        float twr = ((half & m0) & 1) ? -1.0f : 1.0f;
        float twi = 0.0f;
        float ar = 0.0f, ai = 0.0f;
        int base = half << 5;             // k1 start
        #pragma unroll
        for (int k = 0; k < 32; ++k) {
            float v = sHs[((base + k) << 6) + k0];
            ar = fmaf(v, twr, ar);
            ai = fmaf(v, twi, ai);
            float nr = fmaf(twr, rr, -(twi * ri));
            twi      = fmaf(twr, ri,   twi * rr);
            twr = nr;
        }
        sP[tid] = make_float2(ar, ai);
    }
    __syncthreads();
    if (tid < 256) {                      // combine halves: sY[m0j][k0]
        float2 a = sP[tid], c = sP[256 + tid];
        sY[tid] = make_float2(a.x + c.x, a.y + c.y);
    }
    __syncthreads();

    {   // stage B partial: tid = half*256 + m0j*64 + m1
        int m1   = tid & 63;
        int m0j  = (tid >> 6) & 3;
        int half = tid >> 8;
        int m    = (m1 << 6) + m0b + m0j;
        float mrev = (float)m * (1.0f / 4096.0f);
        float rr =  cos_rev(mrev);
        float ri = -sin_rev(mrev);        // rot = e^{-2pi i m/4096}
        // init tw = e^{-2pi i (32*half*m)/4096}
        float irev = (float)((m * (half << 5)) & 4095) * (1.0f / 4096.0f);
        float twr =  cos_rev(irev);
        float twi = -sin_rev(irev);
        float ar = 0.0f, ai = 0.0f;
        int base = half << 5;             // k0 start
        #pragma unroll
        for (int k = 0; k < 32; ++k) {
            float2 y = sY[(m0j << 6) + base + k];     // wave-broadcast
            ar = fmaf(y.x, twr, fmaf(-y.y, twi, ar));
            ai = fmaf(y.x, twi, fmaf( y.y, twr, ai));
            float nr = fmaf(twr, rr, -(twi * ri));
            twi      = fmaf(twr, ri,   twi * rr);
            twr = nr;
        }
        sP[tid] = make_float2(ar, ai);
    }
    __syncthreads();
    if (tid < 256) {                      // combine halves, write out
        int m1 = tid & 63, m0j = tid >> 6;
        float2 a = sP[tid], c = sP[256 + tid];
        int m = (m1 << 6) + m0b + m0j;
        g_Hft[d * M_COLS + m] = make_float2(a.x + c.x, a.y + c.y);
    }
}

// ---------------------------------------------------------------------------
// Main (R13 verbatim — 19.2us-proven). Hermitian mirror + per-(n,d) table.
// For m = 1+m0+j*1024:  u = e^{+i 2pi tau m/M}
//   zr = ur*hr + ui*hi ; zi = ur*hi - ui*hr
//   Re V[n,m]      += ws * zr
//   Re V[n,4096-m] += wcr*zr + wci*zi
// grid (4,512) = 2048 blocks = 8 waves/SIMD.
// ---------------------------------------------------------------------------
__global__ void shiftnmf_main(float* __restrict__ out) {
    int tid = threadIdx.x;
    int m0  = blockIdx.x * 256 + tid;     // 0..1023 ; m_j = 1 + m0 + j*1024
    int n0  = blockIdx.y * R_ROWS;

    float fm0 = (float)(1 + m0) * (1.0f / (float)M_COLS);

    float accm[R_ROWS][T_PTS];            // direct outputs, m
    float accx[R_ROWS][T_PTS];            // mirror outputs, 4096-m
    #pragma unroll
    for (int r = 0; r < R_ROWS; ++r)
        #pragma unroll
        for (int j = 0; j < T_PTS; ++j) { accm[r][j] = 0.0f; accx[r][j] = 0.0f; }

    #pragma unroll
    for (int d = 0; d < RANK; ++d) {
        float ur[R_ROWS], ui[R_ROWS];                 // unit phasor (per-lane)
        float vr[R_ROWS], vi[R_ROWS];                 // step (SGPR)
        float ws[R_ROWS], wcr[R_ROWS], wci[R_ROWS];   // weights (SGPR)
        #pragma unroll
        for (int r = 0; r < R_ROWS; ++r) {
            int nd = (n0 + r) * RANK + d;
            float4 t4 = g_Tab4[nd];                   // block-uniform
            vr[r]  = rfl(t4.x);  vi[r]  = rfl(t4.y);
            wcr[r] = rfl(t4.z);  wci[r] = rfl(t4.w);
            ws[r]  = rfl(g_Tab2[nd].x);
            float tv = rfl(g_Tab2[nd].y);
            float r0 = fract_f(tv * fm0);             // only per-thread trig
            ur[r] = cos_rev(r0);                      // u = e^{+i 2pi tau m_0/M}
            ui[r] = sin_rev(r0);
        }

        const float2* hp = g_Hft + d * M_COLS + 1 + m0;
        #pragma unroll
        for (int j = 0; j < T_PTS; ++j) {
            float2 h = hp[j * M_STRIDE];              // coalesced, L2-resident
            #pragma unroll
            for (int r = 0; r < R_ROWS; ++r) {
                float t1v = ui[r] * h.y;
                float zr = fmaf(ur[r], h.x, t1v);     // Re(conj(u)h)
                float t2v = ui[r] * h.x;
                float zi = fmaf(ur[r], h.y, -t2v);    // Im(conj(u)h)
                accm[r][j] = fmaf(ws[r],  zr, accm[r][j]);
                accx[r][j] = fmaf(wcr[r], zr, fmaf(wci[r], zi, accx[r][j]));
                if (j < T_PTS - 1) {                  // u *= v (skip dead last)
                    float nr = fmaf(ur[r], vr[r], -(ui[r] * vi[r]));
                    ui[r]    = fmaf(ur[r], vi[r],   ui[r] * vr[r]);
                    ur[r]    = nr;
                }
            }
        }
    }

    #pragma unroll
    for (int r = 0; r < R_ROWS; ++r) {
        float* op = out + (n0 + r) * M_COLS;
        #pragma unroll
        for (int j = 0; j < T_PTS; ++j)
            op[1 + m0 + j * M_STRIDE] = accm[r][j];    // m in [1,2048]
        #pragma unroll
        for (int j = 0; j < T_PTS; ++j)
            op[4095 - m0 - j * M_STRIDE] = accx[r][j]; // 4096-m in [2048,4095]
    }

    if (blockIdx.x == 0 && tid == 0) {                // column 0, direct
        #pragma unroll
        for (int r = 0; r < R_ROWS; ++r) {
            int n = n0 + r;
            float a = 0.0f;
            #pragma unroll
            for (int d = 0; d < RANK; ++d)
                a = fmaf(g_Tab2[n * RANK + d].x, g_Hft[d * M_COLS].x, a);
            out[n * M_COLS] = a;
        }
    }
}

extern "C" void kernel_launch(void* const* d_in, const int* in_sizes, int n_in,
                              void* d_out, int out_size, void* d_ws, size_t ws_size,
                              hipStream_t stream) {
    const float* W   = (const float*)d_in[0];   // [1024, 8]
    const float* H   = (const float*)d_in[1];   // [8, 4096]
    const float* tau = (const float*)d_in[2];   // [1024, 8]

    fft_fused<<<dim3(128), dim3(512), 0, stream>>>(H, W, tau);

    dim3 grid(M_COLS / 2 / (256 * T_PTS), N_ROWS / R_ROWS);  // (4, 512)
    shiftnmf_main<<<grid, dim3(256), 0, stream>>>((float*)d_out);
}